// Round 1
// baseline (3001.152 us; speedup 1.0000x reference)
//
#include <hip/hip_runtime.h>

// GCN: 4 layers, N=100000 nodes, E=1600000 edges, dims 256->128->64->16->40.
// Reference: deg_out/deg_in via segment_sum of ones (clamped >=1),
// norm = rsqrt(deg). Per layer: h = (h*norm_src)@W; h = scatter_sum(h[src], dst);
// h = h*norm_dst + b; ReLU except last layer.

#define NBLK_CAP 60000

__global__ void k_deg(const int* __restrict__ src, const int* __restrict__ dst,
                      float* __restrict__ degA, float* __restrict__ degB, int E) {
    int stride = gridDim.x * blockDim.x;
    for (int i = blockIdx.x * blockDim.x + threadIdx.x; i < E; i += stride) {
        atomicAdd(&degA[src[i]], 1.0f);
        atomicAdd(&degB[dst[i]], 1.0f);
    }
}

__global__ void k_norm(float* __restrict__ degA, float* __restrict__ degB, int N) {
    int stride = gridDim.x * blockDim.x;
    for (int i = blockIdx.x * blockDim.x + threadIdx.x; i < N; i += stride) {
        degA[i] = rsqrtf(fmaxf(degA[i], 1.0f));
        degB[i] = rsqrtf(fmaxf(degB[i], 1.0f));
    }
}

// out[n,j] = norm[n] * sum_k in[n,k] * W[k,j]
__global__ void k_proj(const float* __restrict__ in, const float* __restrict__ norm,
                       const float* __restrict__ W, float* __restrict__ out,
                       int N, int din, int dout) {
    int total = N * dout;
    int stride = gridDim.x * blockDim.x;
    for (int i = blockIdx.x * blockDim.x + threadIdx.x; i < total; i += stride) {
        int n = i / dout;
        int j = i - n * dout;
        const float* row = in + (long)n * din;
        float acc = 0.0f;
        for (int k = 0; k < din; ++k)
            acc += row[k] * W[k * dout + j];
        out[i] = acc * norm[n];
    }
}

// agg[dst[e], f] += proj[src[e], f]
__global__ void k_agg(const int* __restrict__ src, const int* __restrict__ dst,
                      const float* __restrict__ proj, float* __restrict__ agg,
                      int E, int dout) {
    int total = E * dout;  // max 204.8M < 2^31
    int stride = gridDim.x * blockDim.x;
    for (int i = blockIdx.x * blockDim.x + threadIdx.x; i < total; i += stride) {
        int e = i / dout;
        int f = i - e * dout;
        int s = src[e];
        int d = dst[e];
        atomicAdd(&agg[(long)d * dout + f], proj[(long)s * dout + f]);
    }
}

// out[n,f] = act(agg[n,f]*norm[n] + bias[f])
__global__ void k_post(const float* __restrict__ agg, const float* __restrict__ norm,
                       const float* __restrict__ bias, float* __restrict__ out,
                       int N, int dout, int relu) {
    int total = N * dout;
    int stride = gridDim.x * blockDim.x;
    for (int i = blockIdx.x * blockDim.x + threadIdx.x; i < total; i += stride) {
        int n = i / dout;
        int f = i - n * dout;
        float v = agg[i] * norm[n] + bias[f];
        out[i] = relu ? fmaxf(v, 0.0f) : v;
    }
}

static inline int iminv(int a, int b) { return a < b ? a : b; }

extern "C" void kernel_launch(void* const* d_in, const int* in_sizes, int n_in,
                              void* d_out, int out_size, void* d_ws, size_t ws_size,
                              hipStream_t stream) {
    const float* x   = (const float*)d_in[0];
    const int*   src = (const int*)d_in[1];
    const int*   dst = (const int*)d_in[2];
    const float* Ws[4] = { (const float*)d_in[3], (const float*)d_in[5],
                           (const float*)d_in[7], (const float*)d_in[9] };
    const float* bs[4] = { (const float*)d_in[4], (const float*)d_in[6],
                           (const float*)d_in[8], (const float*)d_in[10] };

    const int N = in_sizes[0] / 256;
    const int E = in_sizes[1];
    const int dims[5] = { 256, 128, 64, 16, 40 };

    float* ws    = (float*)d_ws;
    float* normS = ws;            // [N]  rsqrt(deg_out)
    float* normD = ws + N;        // [N]  rsqrt(deg_in)
    float* pa    = ws + 2 * (size_t)N;            // [N*128]
    float* pb    = pa + (size_t)N * 128;          // [N*128]

    // --- degrees -> norms ---
    hipMemsetAsync(normS, 0, 2 * (size_t)N * sizeof(float), stream);
    k_deg<<<2048, 256, 0, stream>>>(src, dst, normS, normD, E);
    k_norm<<<(N + 255) / 256, 256, 0, stream>>>(normS, normD, N);

    // --- 4 GCN layers, ping-pong pa/pb ---
    const float* in = x;
    for (int l = 0; l < 4; ++l) {
        int din = dims[l], dout = dims[l + 1];
        int total = N * dout;

        // proj: in -> pa
        k_proj<<<iminv((total + 255) / 256, NBLK_CAP), 256, 0, stream>>>(
            in, normS, Ws[l], pa, N, din, dout);

        // zero agg target, scatter: pa -> pb
        hipMemsetAsync(pb, 0, (size_t)total * sizeof(float), stream);
        k_agg<<<16384, 256, 0, stream>>>(src, dst, pa, pb, E, dout);

        // epilogue: pb -> dest (pa, or d_out for last layer)
        float* dest = (l == 3) ? (float*)d_out : pa;
        k_post<<<iminv((total + 255) / 256, NBLK_CAP), 256, 0, stream>>>(
            pb, normD, bs[l], dest, N, dout, l < 3 ? 1 : 0);

        in = dest;
        // swap roles: next proj writes old pb, aggregates into old pa
        float* t = pa; pa = pb; pb = t;
    }
}